// Round 1
// baseline (1281.341 us; speedup 1.0000x reference)
//
#include <hip/hip_runtime.h>
#include <hip/hip_bf16.h>

// Problem constants
#define NB 16      // batch
#define MM 1024    // nodes
#define DD 64      // dim
#define HH 4       // heads
#define NEG 0.2f

// ---------------- Kernel 1: K/Q/V projections ----------------
// grid: N*M blocks, 256 threads. Each block handles one (n,m) row of x.
// thread t -> h = t/64, e = t%64; computes K/Q/V[n,h,m,e].
__global__ __launch_bounds__(256) void proj_kernel(
    const float* __restrict__ x,
    const float* __restrict__ Wk, const float* __restrict__ bk,
    const float* __restrict__ Wq, const float* __restrict__ bq,
    const float* __restrict__ Wv, const float* __restrict__ bv,
    float* __restrict__ Kg, float* __restrict__ Qg, float* __restrict__ Vg) {
  __shared__ float4 xs[16];
  const int nm = blockIdx.x;            // n*M + m
  const int n = nm >> 10, m = nm & 1023;
  const int t = threadIdx.x;
  if (t < 16) xs[t] = ((const float4*)(x + (size_t)nm * DD))[t];
  __syncthreads();

  const int h = t >> 6, e = t & 63;
  const int we = h * DD + e;            // row index into stacked (H*D, D) weights
  const float4* wk = (const float4*)(Wk + (size_t)we * DD);
  const float4* wq = (const float4*)(Wq + (size_t)we * DD);
  const float4* wv = (const float4*)(Wv + (size_t)we * DD);

  float sk = 0.f, sq = 0.f, sv = 0.f;
#pragma unroll
  for (int c = 0; c < 16; ++c) {
    const float4 xv = xs[c];
    const float4 a = wk[c], b = wq[c], cv = wv[c];
    sk += xv.x * a.x + xv.y * a.y + xv.z * a.z + xv.w * a.w;
    sq += xv.x * b.x + xv.y * b.y + xv.z * b.z + xv.w * b.w;
    sv += xv.x * cv.x + xv.y * cv.y + xv.z * cv.z + xv.w * cv.w;
  }
  const size_t oi = (((size_t)n * HH + h) * MM + m) * DD + e;
  Kg[oi] = sk + bk[we];
  Qg[oi] = sq + bq[we];
  Vg[oi] = sv + bv[we];
}

// ---------------- Kernel 2: flash attention + dx epilogue ----------------
// grid: (M/64, H, N), 256 threads. Block owns 64 i-rows (K rows).
// thread t -> i_l = t/4 (row), q = t%4 (owns e-range q*16..q*16+15 and j-range q*16.. for scores)
#define BI 64
#define BJ 64
#define LSTR 68   // LDS row stride in floats: 68*4B=272B, 16B-aligned, odd/4 -> conflict-free-ish

__global__ __launch_bounds__(256) void attn_kernel(
    const float* __restrict__ Kg, const float* __restrict__ Qg,
    const float* __restrict__ Vg, const float* __restrict__ x,
    float* __restrict__ dx) {
  __shared__ float Qs[BJ * LSTR];
  __shared__ float Vs[BJ * LSTR];
  __shared__ float Ss[BI * LSTR];

  const int t = threadIdx.x;
  const int i_l = t >> 2, q = t & 3;
  const int it = blockIdx.x, h = blockIdx.y, n = blockIdx.z;
  const int i0 = it * BI;

  const size_t nh_base = ((size_t)n * HH + h) * MM * DD;
  const float* Kbase = Kg + nh_base;
  const float* Qbase = Qg + nh_base;
  const float* Vbase = Vg + nh_base;

  // Stage K tile through Ss (coalesced), then pull this thread's row into regs.
#pragma unroll
  for (int rep = 0; rep < 4; ++rep) {
    const int idx4 = rep * 256 + t;        // 1024 float4s = 64x64 floats
    const int row = idx4 >> 4, c4 = idx4 & 15;
    const float4 v = ((const float4*)(Kbase + (size_t)(i0 + row) * DD))[c4];
    *(float4*)&Ss[row * LSTR + c4 * 4] = v;
  }
  __syncthreads();
  float4 kreg[16];
#pragma unroll
  for (int c = 0; c < 16; ++c) kreg[c] = *(float4*)&Ss[i_l * LSTR + c * 4];

  float4 acc[4];
#pragma unroll
  for (int c = 0; c < 4; ++c) acc[c] = make_float4(0.f, 0.f, 0.f, 0.f);
  float m_i = -1e30f, l_i = 0.f;

  for (int jt = 0; jt < MM / BJ; ++jt) {
    __syncthreads();  // protect Qs/Vs/Ss reuse across iterations (and kreg reads at jt=0)
#pragma unroll
    for (int rep = 0; rep < 4; ++rep) {
      const int idx4 = rep * 256 + t;
      const int row = idx4 >> 4, c4 = idx4 & 15;
      const int jg = jt * BJ + row;
      *(float4*)&Qs[row * LSTR + c4 * 4] = ((const float4*)(Qbase + (size_t)jg * DD))[c4];
      *(float4*)&Vs[row * LSTR + c4 * 4] = ((const float4*)(Vbase + (size_t)jg * DD))[c4];
    }
    __syncthreads();

    // scores for j = q*16 + jj, leaky-relu, write to Ss[i_l][j]
#pragma unroll
    for (int jj = 0; jj < 16; ++jj) {
      const int j = q * 16 + jj;
      float s = 0.f;
#pragma unroll
      for (int c = 0; c < 16; ++c) {
        const float4 a = kreg[c];
        const float4 b = *(float4*)&Qs[j * LSTR + c * 4];
        s += a.x * b.x + a.y * b.y + a.z * b.z + a.w * b.w;
      }
      s = s > 0.f ? s : NEG * s;
      Ss[i_l * LSTR + j] = s;
    }
    __syncthreads();

    // online softmax update over this j-tile (4 q-threads per row do identical m/l math)
    float mt = -1e30f;
#pragma unroll
    for (int j = 0; j < BJ; ++j) mt = fmaxf(mt, Ss[i_l * LSTR + j]);
    const float m_new = fmaxf(m_i, mt);
    const float scale = __expf(m_i - m_new);
#pragma unroll
    for (int c = 0; c < 4; ++c) {
      acc[c].x *= scale; acc[c].y *= scale; acc[c].z *= scale; acc[c].w *= scale;
    }
    float lsum = 0.f;
    for (int j = 0; j < BJ; ++j) {
      const float p = __expf(Ss[i_l * LSTR + j] - m_new);
      lsum += p;
      const float* vrow = &Vs[j * LSTR + q * 16];
#pragma unroll
      for (int c = 0; c < 4; ++c) {
        const float4 vv = *(const float4*)&vrow[c * 4];
        acc[c].x += p * vv.x; acc[c].y += p * vv.y;
        acc[c].z += p * vv.z; acc[c].w += p * vv.w;
      }
    }
    l_i = l_i * scale + lsum;
    m_i = m_new;
  }

  // epilogue: agg = acc/l; dx = leaky(agg) - x ; store concat layout (n, m, h*D+e)
  const float inv = 1.0f / l_i;
  const int ig = i0 + i_l;
  const float* xrow = x + ((size_t)n * MM + ig) * DD + q * 16;
  float* orow = dx + ((size_t)n * MM + ig) * (HH * DD) + h * DD + q * 16;
#pragma unroll
  for (int c = 0; c < 4; ++c) {
    const float4 xv = *(const float4*)&xrow[c * 4];
    float4 o;
    float v;
    v = acc[c].x * inv; v = v > 0.f ? v : NEG * v; o.x = v - xv.x;
    v = acc[c].y * inv; v = v > 0.f ? v : NEG * v; o.y = v - xv.y;
    v = acc[c].z * inv; v = v > 0.f ? v : NEG * v; o.z = v - xv.z;
    v = acc[c].w * inv; v = v > 0.f ? v : NEG * v; o.w = v - xv.w;
    *(float4*)&orow[c * 4] = o;
  }
}

// ---------------- Kernel 3: decoder GEMM ----------------
// out[r, d] = dx[r, :] . Wdec[d, :] + bdec[d]   (r = n*M+m, 256-length dot)
// grid: N*M/4 blocks, 256 threads: 4 rows x 64 d per block.
__global__ __launch_bounds__(256) void dec_kernel(
    const float* __restrict__ dx, const float* __restrict__ Wdec,
    const float* __restrict__ bdec, float* __restrict__ out) {
  __shared__ float4 dxs[4][64];
  const int t = threadIdx.x;
  const int r0 = blockIdx.x * 4;
  {
    const int row = t >> 6, c4 = t & 63;
    dxs[row][c4] = ((const float4*)(dx + (size_t)(r0 + row) * (HH * DD)))[c4];
  }
  __syncthreads();
  const int row = t >> 6, d = t & 63;
  const float4* w = (const float4*)(Wdec + (size_t)d * (HH * DD));
  float s = bdec[d];
#pragma unroll
  for (int c = 0; c < 64; ++c) {
    const float4 a = dxs[row][c];
    const float4 b = w[c];
    s += a.x * b.x + a.y * b.y + a.z * b.z + a.w * b.w;
  }
  out[(size_t)(r0 + row) * DD + d] = s;
}

extern "C" void kernel_launch(void* const* d_in, const int* in_sizes, int n_in,
                              void* d_out, int out_size, void* d_ws, size_t ws_size,
                              hipStream_t stream) {
  const float* x    = (const float*)d_in[0];
  // d_in[1] = edge (unused)
  const float* Wk   = (const float*)d_in[2];
  const float* bk   = (const float*)d_in[3];
  const float* Wq   = (const float*)d_in[4];
  const float* bq   = (const float*)d_in[5];
  const float* Wv   = (const float*)d_in[6];
  const float* bv   = (const float*)d_in[7];
  const float* Wdec = (const float*)d_in[8];
  const float* bdec = (const float*)d_in[9];
  float* out = (float*)d_out;

  // workspace layout (floats): K | Q | V | dx  — each N*H*M*D = 4,194,304 floats
  const size_t seg = (size_t)NB * HH * MM * DD;
  float* Kg = (float*)d_ws;
  float* Qg = Kg + seg;
  float* Vg = Qg + seg;
  float* DX = Vg + seg;

  proj_kernel<<<NB * MM, 256, 0, stream>>>(x, Wk, bk, Wq, bq, Wv, bv, Kg, Qg, Vg);

  dim3 agrid(MM / BI, HH, NB);
  attn_kernel<<<agrid, 256, 0, stream>>>(Kg, Qg, Vg, x, DX);

  dec_kernel<<<NB * MM / 4, 256, 0, stream>>>(DX, Wdec, bdec, out);
}

// Round 2
// 215.132 us; speedup vs baseline: 5.9561x; 5.9561x over previous
//
#include <hip/hip_runtime.h>
#include <hip/hip_bf16.h>

// Node_GAT: N=16, M=1024, D=64, H=4. out = dec(leaky(softmax(leaky(K Q^T)) V) - x)
// R2: full MFMA pipeline. S-GEMM in split-bf16 (hi+lo) for fp32-like precision;
// softmax without max-subtraction (scores bounded: leaky keeps min > -15, max ~60,
// exp fits fp32) -> P = exp(leaky(S)) unnormalized, l via ones-MFMA, divide at end.

#define NB 16
#define MM 1024
#define DD 64
#define HH 4
#define NEG 0.2f

typedef __attribute__((ext_vector_type(8))) short bf16x8;
typedef __attribute__((ext_vector_type(4))) float f32x4;

__device__ inline unsigned short f2bf(float f) {
  unsigned int u = __builtin_bit_cast(unsigned int, f);
  unsigned int r = (u + 0x7FFFu + ((u >> 16) & 1u)) >> 16;
  return (unsigned short)r;
}
__device__ inline float bf2f(unsigned short b) {
  unsigned int u = ((unsigned int)b) << 16;
  return __builtin_bit_cast(float, u);
}

// ---------------- Kernel 1: projections (VALU fp32, tiled for weight reuse) ----------
// grid (128, 12): x-tile of 128 rows, combo = mat(3) x head(4). Emits hi/lo bf16 for
// K,Q (split precision) and single bf16 for V, laid out (N,H,M,D).
#define PXS 68  // fp32 LDS stride (16B-aligned rows)

__global__ __launch_bounds__(256) void proj_kernel(
    const float* __restrict__ x,
    const float* __restrict__ Wk, const float* __restrict__ bk,
    const float* __restrict__ Wq, const float* __restrict__ bq,
    const float* __restrict__ Wv, const float* __restrict__ bv,
    unsigned short* __restrict__ Khi, unsigned short* __restrict__ Klo,
    unsigned short* __restrict__ Qhi, unsigned short* __restrict__ Qlo,
    unsigned short* __restrict__ Vb) {
  __shared__ float xs[128 * PXS];
  __shared__ float ws[64 * PXS];
  const int t = threadIdx.x;
  const int r0 = blockIdx.x * 128;
  const int combo = blockIdx.y;
  const int mat = combo >> 2, h = combo & 3;
  const float* W = mat == 0 ? Wk : (mat == 1 ? Wq : Wv);
  const float* bias = mat == 0 ? bk : (mat == 1 ? bq : bv);

#pragma unroll
  for (int rep = 0; rep < 8; ++rep) {
    int idx = rep * 256 + t;
    int row = idx >> 4, c4 = (idx & 15) * 4;
    *(float4*)&xs[row * PXS + c4] = *(const float4*)&x[(size_t)(r0 + row) * DD + c4];
  }
#pragma unroll
  for (int rep = 0; rep < 4; ++rep) {
    int idx = rep * 256 + t;
    int row = idx >> 4, c4 = (idx & 15) * 4;
    *(float4*)&ws[row * PXS + c4] = *(const float4*)&W[((size_t)h * DD + row) * DD + c4];
  }
  __syncthreads();

  const int mg = t >> 3, eg = t & 7;  // rows mg+32c (c<4), cols eg+8s (s<8)
  float acc[4][8];
#pragma unroll
  for (int c = 0; c < 4; ++c)
#pragma unroll
    for (int s = 0; s < 8; ++s) acc[c][s] = 0.f;

  for (int k4 = 0; k4 < 16; ++k4) {
    float4 xa[4], wb[8];
#pragma unroll
    for (int c = 0; c < 4; ++c) xa[c] = *(float4*)&xs[(mg + 32 * c) * PXS + k4 * 4];
#pragma unroll
    for (int s = 0; s < 8; ++s) wb[s] = *(float4*)&ws[(eg + 8 * s) * PXS + k4 * 4];
#pragma unroll
    for (int c = 0; c < 4; ++c)
#pragma unroll
      for (int s = 0; s < 8; ++s)
        acc[c][s] += xa[c].x * wb[s].x + xa[c].y * wb[s].y +
                     xa[c].z * wb[s].z + xa[c].w * wb[s].w;
  }

  float bvals[8];
#pragma unroll
  for (int s = 0; s < 8; ++s) bvals[s] = bias[h * DD + eg + 8 * s];

  __syncthreads();  // done reading xs; reuse as bf16 repack buffer
  unsigned short* xb = (unsigned short*)xs;  // [128][72] bf16
  unsigned short hb[4][8];
#pragma unroll
  for (int c = 0; c < 4; ++c)
#pragma unroll
    for (int s = 0; s < 8; ++s) {
      float v = acc[c][s] + bvals[s];
      unsigned short hbits = f2bf(v);
      hb[c][s] = hbits;
      xb[(mg + 32 * c) * 72 + eg + 8 * s] = hbits;
    }
  __syncthreads();
  unsigned short* dsthi = mat == 0 ? Khi : (mat == 1 ? Qhi : Vb);
#pragma unroll
  for (int rep = 0; rep < 4; ++rep) {
    int idx = rep * 256 + t;
    int row = idx >> 3, c8 = (idx & 7) * 8;
    int gr = r0 + row, nn = gr >> 10, mmi = gr & 1023;
    size_t di = (((size_t)nn * HH + h) * MM + mmi) * DD + c8;
    *(uint4*)&dsthi[di] = *(uint4*)&xb[row * 72 + c8];
  }
  if (mat < 2) {
    __syncthreads();
#pragma unroll
    for (int c = 0; c < 4; ++c)
#pragma unroll
      for (int s = 0; s < 8; ++s) {
        float v = acc[c][s] + bvals[s];
        xb[(mg + 32 * c) * 72 + eg + 8 * s] = f2bf(v - bf2f(hb[c][s]));
      }
    __syncthreads();
    unsigned short* dstlo = mat == 0 ? Klo : Qlo;
#pragma unroll
    for (int rep = 0; rep < 4; ++rep) {
      int idx = rep * 256 + t;
      int row = idx >> 3, c8 = (idx & 7) * 8;
      int gr = r0 + row, nn = gr >> 10, mmi = gr & 1023;
      size_t di = (((size_t)nn * HH + h) * MM + mmi) * DD + c8;
      *(uint4*)&dstlo[di] = *(uint4*)&xb[row * 72 + c8];
    }
  }
}

// ---------------- Kernel 2: MFMA flash attention ----------------
// grid (16, H, N), 256 thr = 4 waves. Block: 64 i-rows (K rows) x all 1024 j.
// Wave w owns i-rows w*16..w*16+15. S = Khi*Qhi + Khi*Qlo + Klo*Qhi (split bf16),
// P = exp(leaky(S)) -> bf16 -> LDS -> A-frags; agg += P*V, l += P*ones. No max needed.
#define AST 72  // bf16 LDS stride

__global__ __launch_bounds__(256) void attn_kernel(
    const unsigned short* __restrict__ Khi, const unsigned short* __restrict__ Klo,
    const unsigned short* __restrict__ Qhig, const unsigned short* __restrict__ Qlog,
    const unsigned short* __restrict__ Vb, const float* __restrict__ x,
    unsigned short* __restrict__ DX) {
  __shared__ unsigned short qh[64 * AST];
  __shared__ unsigned short ql[64 * AST];
  __shared__ unsigned short vt[64 * AST];  // V transposed: [e][j]
  __shared__ unsigned short ps[64 * AST];  // P tiles: [i_local][j_local], wave-partitioned

  const int t = threadIdx.x;
  const int w = t >> 6, lane = t & 63;
  const int L15 = lane & 15, q = lane >> 4;
  const int i0 = blockIdx.x * 64, h = blockIdx.y, n = blockIdx.z;
  const size_t base = (((size_t)n * HH + h) * MM) * DD;

  // stage K tile (hi->qh, lo->ql), pull A-frags to regs
#pragma unroll
  for (int rep = 0; rep < 2; ++rep) {
    int idx = rep * 256 + t;
    int row = idx >> 3, c8 = (idx & 7) * 8;
    *(uint4*)&qh[row * AST + c8] = *(const uint4*)&Khi[base + (size_t)(i0 + row) * DD + c8];
    *(uint4*)&ql[row * AST + c8] = *(const uint4*)&Klo[base + (size_t)(i0 + row) * DD + c8];
  }
  __syncthreads();
  bf16x8 khi[2], klo[2];
#pragma unroll
  for (int kt = 0; kt < 2; ++kt) {
    khi[kt] = *(bf16x8*)&qh[(w * 16 + L15) * AST + kt * 32 + q * 8];
    klo[kt] = *(bf16x8*)&ql[(w * 16 + L15) * AST + kt * 32 + q * 8];
  }

  f32x4 agg[4], accl;
#pragma unroll
  for (int es = 0; es < 4; ++es) agg[es] = (f32x4){0.f, 0.f, 0.f, 0.f};
  accl = (f32x4){0.f, 0.f, 0.f, 0.f};
  bf16x8 ones;
#pragma unroll
  for (int i = 0; i < 8; ++i) ones[i] = (short)0x3F80;

  for (int jt = 0; jt < 16; ++jt) {
    __syncthreads();
    const int j0 = jt * 64;
#pragma unroll
    for (int rep = 0; rep < 2; ++rep) {
      int idx = rep * 256 + t;
      int row = idx >> 3, c8 = (idx & 7) * 8;
      *(uint4*)&qh[row * AST + c8] = *(const uint4*)&Qhig[base + (size_t)(j0 + row) * DD + c8];
      *(uint4*)&ql[row * AST + c8] = *(const uint4*)&Qlog[base + (size_t)(j0 + row) * DD + c8];
      uint4 vv = *(const uint4*)&Vb[base + (size_t)(j0 + row) * DD + c8];
      unsigned short* pv = (unsigned short*)&vv;
#pragma unroll
      for (int s2 = 0; s2 < 8; ++s2) vt[(c8 + s2) * AST + row] = pv[s2];
    }
    __syncthreads();

    // S tiles (16i x 16j per jsub) + leaky + exp -> P in LDS
#pragma unroll
    for (int js = 0; js < 4; ++js) {
      f32x4 C = (f32x4){0.f, 0.f, 0.f, 0.f};
#pragma unroll
      for (int kt = 0; kt < 2; ++kt) {
        bf16x8 bh = *(bf16x8*)&qh[(js * 16 + L15) * AST + kt * 32 + q * 8];
        bf16x8 bl = *(bf16x8*)&ql[(js * 16 + L15) * AST + kt * 32 + q * 8];
        C = __builtin_amdgcn_mfma_f32_16x16x32_bf16(khi[kt], bh, C, 0, 0, 0);
        C = __builtin_amdgcn_mfma_f32_16x16x32_bf16(khi[kt], bl, C, 0, 0, 0);
        C = __builtin_amdgcn_mfma_f32_16x16x32_bf16(klo[kt], bh, C, 0, 0, 0);
      }
#pragma unroll
      for (int r = 0; r < 4; ++r) {
        float s = C[r];
        s = s > 0.f ? s : NEG * s;
        ps[(w * 16 + q * 4 + r) * AST + js * 16 + L15] = f2bf(__expf(s));
      }
    }
    // PV + l (wave-local LDS RAW; compiler inserts lgkmcnt waits)
#pragma unroll
    for (int kt = 0; kt < 2; ++kt) {
      bf16x8 aP = *(bf16x8*)&ps[(w * 16 + L15) * AST + kt * 32 + q * 8];
      accl = __builtin_amdgcn_mfma_f32_16x16x32_bf16(aP, ones, accl, 0, 0, 0);
#pragma unroll
      for (int es = 0; es < 4; ++es) {
        bf16x8 bV = *(bf16x8*)&vt[(es * 16 + L15) * AST + kt * 32 + q * 8];
        agg[es] = __builtin_amdgcn_mfma_f32_16x16x32_bf16(aP, bV, agg[es], 0, 0, 0);
      }
    }
  }

  // epilogue: dx = leaky(agg/l) - x, write bf16 in (n, m, h*64+e) concat layout
  float inv[4];
#pragma unroll
  for (int r = 0; r < 4; ++r) inv[r] = 1.0f / accl[r];
#pragma unroll
  for (int es = 0; es < 4; ++es)
#pragma unroll
    for (int r = 0; r < 4; ++r) {
      float v = agg[es][r] * inv[r];
      v = v > 0.f ? v : NEG * v;
      v -= x[((size_t)n * MM + i0 + w * 16 + q * 4 + r) * DD + es * 16 + L15];
      ps[(w * 16 + q * 4 + r) * AST + es * 16 + L15] = f2bf(v);
    }
#pragma unroll
  for (int rep = 0; rep < 2; ++rep) {
    int row = rep * 8 + (lane >> 3), c8 = (lane & 7) * 8;
    uint4 d = *(uint4*)&ps[(w * 16 + row) * AST + c8];
    *(uint4*)&DX[((size_t)n * MM + i0 + w * 16 + row) * (HH * DD) + h * DD + c8] = d;
  }
}

// ---------------- Kernel 3: decoder MFMA GEMM ----------------
// out(16384x64) = dx(16384x256, bf16) . Wdec^T(256x64) + b. 64 rows/block, K=256.
#define DST 264  // bf16 LDS stride for 256-wide rows

__global__ __launch_bounds__(256) void dec_kernel(
    const unsigned short* __restrict__ DX, const float* __restrict__ Wdec,
    const float* __restrict__ bdec, float* __restrict__ out) {
  __shared__ unsigned short dxs[64 * DST];
  __shared__ unsigned short wds[64 * DST];
  const int t = threadIdx.x;
  const int w = t >> 6, lane = t & 63;
  const int L15 = lane & 15, q = lane >> 4;
  const int r0 = blockIdx.x * 64;

#pragma unroll
  for (int rep = 0; rep < 8; ++rep) {
    int idx = rep * 256 + t;
    int row = idx >> 5, c8 = (idx & 31) * 8;
    *(uint4*)&dxs[row * DST + c8] = *(const uint4*)&DX[(size_t)(r0 + row) * 256 + c8];
  }
#pragma unroll
  for (int rep = 0; rep < 16; ++rep) {
    int idx = rep * 256 + t;
    int row = idx >> 6, c4 = (idx & 63) * 4;
    float4 v = *(const float4*)&Wdec[(size_t)row * 256 + c4];
    unsigned int p0 = (unsigned int)f2bf(v.x) | ((unsigned int)f2bf(v.y) << 16);
    unsigned int p1 = (unsigned int)f2bf(v.z) | ((unsigned int)f2bf(v.w) << 16);
    *(unsigned int*)&wds[row * DST + c4] = p0;
    *(unsigned int*)&wds[row * DST + c4 + 2] = p1;
  }
  __syncthreads();

  f32x4 C[4];
#pragma unroll
  for (int nt = 0; nt < 4; ++nt) C[nt] = (f32x4){0.f, 0.f, 0.f, 0.f};
#pragma unroll
  for (int kt = 0; kt < 8; ++kt) {
    bf16x8 aD = *(bf16x8*)&dxs[(w * 16 + L15) * DST + kt * 32 + q * 8];
#pragma unroll
    for (int nt = 0; nt < 4; ++nt) {
      bf16x8 bW = *(bf16x8*)&wds[(nt * 16 + L15) * DST + kt * 32 + q * 8];
      C[nt] = __builtin_amdgcn_mfma_f32_16x16x32_bf16(aD, bW, C[nt], 0, 0, 0);
    }
  }
#pragma unroll
  for (int nt = 0; nt < 4; ++nt) {
    float bb = bdec[nt * 16 + L15];
#pragma unroll
    for (int r = 0; r < 4; ++r)
      out[(size_t)(r0 + w * 16 + q * 4 + r) * DD + nt * 16 + L15] = C[nt][r] + bb;
  }
}

extern "C" void kernel_launch(void* const* d_in, const int* in_sizes, int n_in,
                              void* d_out, int out_size, void* d_ws, size_t ws_size,
                              hipStream_t stream) {
  const float* x    = (const float*)d_in[0];
  const float* Wk   = (const float*)d_in[2];
  const float* bk   = (const float*)d_in[3];
  const float* Wq   = (const float*)d_in[4];
  const float* bq   = (const float*)d_in[5];
  const float* Wv   = (const float*)d_in[6];
  const float* bv   = (const float*)d_in[7];
  const float* Wdec = (const float*)d_in[8];
  const float* bdec = (const float*)d_in[9];
  float* out = (float*)d_out;

  // ws (bf16 units): Khi | Klo | Qhi | Qlo | Vb | DX, each N*H*M*D = 4194304
  const size_t seg = (size_t)NB * HH * MM * DD;
  unsigned short* Khi = (unsigned short*)d_ws;
  unsigned short* Klo = Khi + seg;
  unsigned short* Qhi = Klo + seg;
  unsigned short* Qlo = Qhi + seg;
  unsigned short* Vb  = Qlo + seg;
  unsigned short* DXp = Vb + seg;

  proj_kernel<<<dim3(128, 12), 256, 0, stream>>>(x, Wk, bk, Wq, bq, Wv, bv,
                                                 Khi, Klo, Qhi, Qlo, Vb);
  attn_kernel<<<dim3(16, HH, NB), 256, 0, stream>>>(Khi, Klo, Qhi, Qlo, Vb, x, DXp);
  dec_kernel<<<NB * MM / 64, 256, 0, stream>>>(DXp, Wdec, bdec, out);
}

// Round 3
// 200.919 us; speedup vs baseline: 6.3774x; 1.0707x over previous
//
#include <hip/hip_runtime.h>
#include <hip/hip_bf16.h>

// Node_GAT N=16, M=1024, D=64, H=4.
// R3: all-MFMA pipeline. proj is a split-bf16 (hi+lo) MFMA GEMM; V is stored
// TRANSPOSED (Vt[n,h,e,m]) so attn stages it with b128 (R2's 8-way-conflict
// scalar transpose removed). Softmax stays max-free: P = exp(leaky(S)) bounded.

#define NB 16
#define MM 1024
#define DD 64
#define HH 4
#define NEG 0.2f

typedef __attribute__((ext_vector_type(8))) short bf16x8;
typedef __attribute__((ext_vector_type(4))) float f32x4;

__device__ inline unsigned short f2bf(float f) {
  unsigned int u = __builtin_bit_cast(unsigned int, f);
  unsigned int r = (u + 0x7FFFu + ((u >> 16) & 1u)) >> 16;
  return (unsigned short)r;
}
__device__ inline float bf2f(unsigned short b) {
  unsigned int u = ((unsigned int)b) << 16;
  return __builtin_bit_cast(float, u);
}

// ---------------- Kernel 0: weight prep ----------------
// Wk|Wq|Wv (16384 fp32 each) -> Whi/Wlo bf16; Wdec (16384) -> Wdb bf16.
// grid 64 x 256 thr x 4 elems.
__global__ __launch_bounds__(256) void prep_kernel(
    const float* __restrict__ Wk, const float* __restrict__ Wq,
    const float* __restrict__ Wv, const float* __restrict__ Wdec,
    unsigned short* __restrict__ Whi, unsigned short* __restrict__ Wlo,
    unsigned short* __restrict__ Wdb) {
  const int b = blockIdx.x, t = threadIdx.x;
  const int seg = b >> 4;                       // 0..2 = K,Q,V; 3 = dec
  const int local = ((b & 15) * 256 + t) * 4;
  const float* src = seg == 0 ? Wk : seg == 1 ? Wq : seg == 2 ? Wv : Wdec;
  float4 v = *(const float4*)&src[local];
  unsigned short h0 = f2bf(v.x), h1 = f2bf(v.y), h2 = f2bf(v.z), h3 = f2bf(v.w);
  uint2 hp;
  hp.x = (unsigned int)h0 | ((unsigned int)h1 << 16);
  hp.y = (unsigned int)h2 | ((unsigned int)h3 << 16);
  if (seg < 3) {
    unsigned short l0 = f2bf(v.x - bf2f(h0)), l1 = f2bf(v.y - bf2f(h1));
    unsigned short l2 = f2bf(v.z - bf2f(h2)), l3 = f2bf(v.w - bf2f(h3));
    uint2 lp;
    lp.x = (unsigned int)l0 | ((unsigned int)l1 << 16);
    lp.y = (unsigned int)l2 | ((unsigned int)l3 << 16);
    *(uint2*)&Whi[seg * 16384 + local] = hp;
    *(uint2*)&Wlo[seg * 16384 + local] = lp;
  } else {
    *(uint2*)&Wdb[local] = hp;
  }
}

// ---------------- Kernel 1: projections, split-bf16 MFMA ----------------
// grid (256, 12): 64 m-rows x combo(mat*4+h). K,Q -> hi/lo (n,h,m,e); V -> Vt (n,h,e,m).
#define PST 72

__global__ __launch_bounds__(256) void proj_kernel(
    const float* __restrict__ x,
    const unsigned short* __restrict__ Whi, const unsigned short* __restrict__ Wlo,
    const float* __restrict__ bk, const float* __restrict__ bq, const float* __restrict__ bv,
    unsigned short* __restrict__ Khi, unsigned short* __restrict__ Klo,
    unsigned short* __restrict__ Qhi, unsigned short* __restrict__ Qlo,
    unsigned short* __restrict__ Vt) {
  __shared__ unsigned short xh[64 * PST];
  __shared__ unsigned short xl[64 * PST];
  __shared__ unsigned short rp[64 * PST];
  const int t = threadIdx.x;
  const int r0 = blockIdx.x * 64;
  const int combo = blockIdx.y, mat = combo >> 2, h = combo & 3;
  const int n = r0 >> 10, ml = r0 & 1023;
  const unsigned short* Wh = Whi + mat * 16384;
  const unsigned short* Wl = Wlo + mat * 16384;
  const float* bias = mat == 0 ? bk : (mat == 1 ? bq : bv);

  // stage x tile as split bf16
#pragma unroll
  for (int rep = 0; rep < 4; ++rep) {
    int idx = rep * 256 + t, row = idx >> 4, c4 = (idx & 15) * 4;
    float4 v = *(const float4*)&x[(size_t)(r0 + row) * DD + c4];
    unsigned short h0 = f2bf(v.x), h1 = f2bf(v.y), h2 = f2bf(v.z), h3 = f2bf(v.w);
    uint2 hp, lp;
    hp.x = (unsigned int)h0 | ((unsigned int)h1 << 16);
    hp.y = (unsigned int)h2 | ((unsigned int)h3 << 16);
    lp.x = (unsigned int)f2bf(v.x - bf2f(h0)) | ((unsigned int)f2bf(v.y - bf2f(h1)) << 16);
    lp.y = (unsigned int)f2bf(v.z - bf2f(h2)) | ((unsigned int)f2bf(v.w - bf2f(h3)) << 16);
    *(uint2*)&xh[row * PST + c4] = hp;
    *(uint2*)&xl[row * PST + c4] = lp;
  }
  __syncthreads();

  const int w = t >> 6, lane = t & 63, L15 = lane & 15, q = lane >> 4;
  bf16x8 ah[2], al[2];
#pragma unroll
  for (int kt = 0; kt < 2; ++kt) {
    ah[kt] = *(bf16x8*)&xh[(w * 16 + L15) * PST + kt * 32 + q * 8];
    al[kt] = *(bf16x8*)&xl[(w * 16 + L15) * PST + kt * 32 + q * 8];
  }

  f32x4 C[4];
  float bb[4];
#pragma unroll
  for (int es = 0; es < 4; ++es) {
    C[es] = (f32x4){0.f, 0.f, 0.f, 0.f};
    const int wrow = h * 64 + es * 16 + L15;
    bb[es] = bias[wrow];
#pragma unroll
    for (int kt = 0; kt < 2; ++kt) {
      bf16x8 bh = *(const bf16x8*)&Wh[(size_t)wrow * 64 + kt * 32 + q * 8];
      bf16x8 bl = *(const bf16x8*)&Wl[(size_t)wrow * 64 + kt * 32 + q * 8];
      C[es] = __builtin_amdgcn_mfma_f32_16x16x32_bf16(ah[kt], bh, C[es], 0, 0, 0);
      C[es] = __builtin_amdgcn_mfma_f32_16x16x32_bf16(ah[kt], bl, C[es], 0, 0, 0);
      C[es] = __builtin_amdgcn_mfma_f32_16x16x32_bf16(al[kt], bh, C[es], 0, 0, 0);
    }
  }

  if (mat < 2) {
    unsigned short* dh = mat == 0 ? Khi : Qhi;
    unsigned short* dl = mat == 0 ? Klo : Qlo;
    const size_t obase = (((size_t)n * HH + h) * MM + ml) * DD;
    // hi pass
#pragma unroll
    for (int es = 0; es < 4; ++es)
#pragma unroll
      for (int r = 0; r < 4; ++r)
        rp[(w * 16 + q * 4 + r) * PST + es * 16 + L15] = f2bf(C[es][r] + bb[es]);
    __syncthreads();
#pragma unroll
    for (int rep = 0; rep < 2; ++rep) {
      int idx = rep * 256 + t, row = idx >> 3, c8 = (idx & 7) * 8;
      *(uint4*)&dh[obase + (size_t)row * DD + c8] = *(uint4*)&rp[row * PST + c8];
    }
    __syncthreads();
    // lo pass
#pragma unroll
    for (int es = 0; es < 4; ++es)
#pragma unroll
      for (int r = 0; r < 4; ++r) {
        float v = C[es][r] + bb[es];
        unsigned short hb = f2bf(v);
        rp[(w * 16 + q * 4 + r) * PST + es * 16 + L15] = f2bf(v - bf2f(hb));
      }
    __syncthreads();
#pragma unroll
    for (int rep = 0; rep < 2; ++rep) {
      int idx = rep * 256 + t, row = idx >> 3, c8 = (idx & 7) * 8;
      *(uint4*)&dl[obase + (size_t)row * DD + c8] = *(uint4*)&rp[row * PST + c8];
    }
  } else {
    // V: transposed repack -> Vt[((n*H+h)*64+e)*1024 + m]
    const size_t obase = (((size_t)n * HH + h) * DD) * MM + ml;
#pragma unroll
    for (int es = 0; es < 4; ++es)
#pragma unroll
      for (int r = 0; r < 4; ++r)
        rp[(es * 16 + L15) * PST + (w * 16 + q * 4 + r)] = f2bf(C[es][r] + bb[es]);
    __syncthreads();
#pragma unroll
    for (int rep = 0; rep < 2; ++rep) {
      int idx = rep * 256 + t, row = idx >> 3, c8 = (idx & 7) * 8;  // row=e, c8=m-chunk
      *(uint4*)&Vt[obase + (size_t)row * MM + c8] = *(uint4*)&rp[row * PST + c8];
    }
  }
}

// ---------------- Kernel 2: MFMA flash attention ----------------
// grid (16, H, N), 256 thr = 4 waves; block = 64 i-rows x all 1024 j.
#define AST 72

__global__ __launch_bounds__(256) void attn_kernel(
    const unsigned short* __restrict__ Khi, const unsigned short* __restrict__ Klo,
    const unsigned short* __restrict__ Qhig, const unsigned short* __restrict__ Qlog,
    const unsigned short* __restrict__ Vt, const float* __restrict__ x,
    unsigned short* __restrict__ DX) {
  __shared__ unsigned short qh[64 * AST];
  __shared__ unsigned short ql[64 * AST];
  __shared__ unsigned short vt[64 * AST];  // [e][j_local]
  __shared__ unsigned short ps[64 * AST];  // P: [i_local][j_local]

  const int t = threadIdx.x;
  const int w = t >> 6, lane = t & 63;
  const int L15 = lane & 15, q = lane >> 4;
  const int i0 = blockIdx.x * 64, h = blockIdx.y, n = blockIdx.z;
  const size_t base = (((size_t)n * HH + h) * MM) * DD;
  const size_t baseT = (((size_t)n * HH + h) * DD) * MM;

  // stage K tile, pull A-frags
#pragma unroll
  for (int rep = 0; rep < 2; ++rep) {
    int idx = rep * 256 + t, row = idx >> 3, c8 = (idx & 7) * 8;
    *(uint4*)&qh[row * AST + c8] = *(const uint4*)&Khi[base + (size_t)(i0 + row) * DD + c8];
    *(uint4*)&ql[row * AST + c8] = *(const uint4*)&Klo[base + (size_t)(i0 + row) * DD + c8];
  }
  __syncthreads();
  bf16x8 khi[2], klo[2];
#pragma unroll
  for (int kt = 0; kt < 2; ++kt) {
    khi[kt] = *(bf16x8*)&qh[(w * 16 + L15) * AST + kt * 32 + q * 8];
    klo[kt] = *(bf16x8*)&ql[(w * 16 + L15) * AST + kt * 32 + q * 8];
  }

  f32x4 agg[4], accl;
#pragma unroll
  for (int es = 0; es < 4; ++es) agg[es] = (f32x4){0.f, 0.f, 0.f, 0.f};
  accl = (f32x4){0.f, 0.f, 0.f, 0.f};
  bf16x8 ones;
#pragma unroll
  for (int i = 0; i < 8; ++i) ones[i] = (short)0x3F80;

  for (int jt = 0; jt < 16; ++jt) {
    __syncthreads();
    const int j0 = jt * 64;
#pragma unroll
    for (int rep = 0; rep < 2; ++rep) {
      int idx = rep * 256 + t, row = idx >> 3, c8 = (idx & 7) * 8;
      *(uint4*)&qh[row * AST + c8] = *(const uint4*)&Qhig[base + (size_t)(j0 + row) * DD + c8];
      *(uint4*)&ql[row * AST + c8] = *(const uint4*)&Qlog[base + (size_t)(j0 + row) * DD + c8];
      *(uint4*)&vt[row * AST + c8] = *(const uint4*)&Vt[baseT + (size_t)row * MM + j0 + c8];
    }
    __syncthreads();

    // S = split-bf16 K.Q^T -> leaky -> exp -> P (bf16) in LDS
#pragma unroll
    for (int js = 0; js < 4; ++js) {
      f32x4 C = (f32x4){0.f, 0.f, 0.f, 0.f};
#pragma unroll
      for (int kt = 0; kt < 2; ++kt) {
        bf16x8 bh = *(bf16x8*)&qh[(js * 16 + L15) * AST + kt * 32 + q * 8];
        bf16x8 bl = *(bf16x8*)&ql[(js * 16 + L15) * AST + kt * 32 + q * 8];
        C = __builtin_amdgcn_mfma_f32_16x16x32_bf16(khi[kt], bh, C, 0, 0, 0);
        C = __builtin_amdgcn_mfma_f32_16x16x32_bf16(khi[kt], bl, C, 0, 0, 0);
        C = __builtin_amdgcn_mfma_f32_16x16x32_bf16(klo[kt], bh, C, 0, 0, 0);
      }
#pragma unroll
      for (int r = 0; r < 4; ++r) {
        float s = C[r];
        s = s > 0.f ? s : NEG * s;
        ps[(w * 16 + q * 4 + r) * AST + js * 16 + L15] = f2bf(__expf(s));
      }
    }
    // PV + row-sum l (wave-local LDS RAW)
#pragma unroll
    for (int kt = 0; kt < 2; ++kt) {
      bf16x8 aP = *(bf16x8*)&ps[(w * 16 + L15) * AST + kt * 32 + q * 8];
      accl = __builtin_amdgcn_mfma_f32_16x16x32_bf16(aP, ones, accl, 0, 0, 0);
#pragma unroll
      for (int es = 0; es < 4; ++es) {
        bf16x8 bV = *(bf16x8*)&vt[(es * 16 + L15) * AST + kt * 32 + q * 8];
        agg[es] = __builtin_amdgcn_mfma_f32_16x16x32_bf16(aP, bV, agg[es], 0, 0, 0);
      }
    }
  }

  // epilogue: dx = leaky(agg/l) - x -> bf16, concat layout (n, m, h*64+e)
  float inv[4];
#pragma unroll
  for (int r = 0; r < 4; ++r) inv[r] = 1.0f / accl[r];
#pragma unroll
  for (int es = 0; es < 4; ++es)
#pragma unroll
    for (int r = 0; r < 4; ++r) {
      float v = agg[es][r] * inv[r];
      v = v > 0.f ? v : NEG * v;
      v -= x[((size_t)n * MM + i0 + w * 16 + q * 4 + r) * DD + es * 16 + L15];
      ps[(w * 16 + q * 4 + r) * AST + es * 16 + L15] = f2bf(v);
    }
#pragma unroll
  for (int rep = 0; rep < 2; ++rep) {
    int row = rep * 8 + (lane >> 3), c8 = (lane & 7) * 8;
    uint4 d = *(uint4*)&ps[(w * 16 + row) * AST + c8];
    *(uint4*)&DX[((size_t)n * MM + i0 + w * 16 + row) * (HH * DD) + h * DD + c8] = d;
  }
}

// ---------------- Kernel 3: decoder MFMA GEMM ----------------
#define DST 264

__global__ __launch_bounds__(256) void dec_kernel(
    const unsigned short* __restrict__ DX, const unsigned short* __restrict__ Wdb,
    const float* __restrict__ bdec, float* __restrict__ out) {
  __shared__ unsigned short dxs[64 * DST];
  __shared__ unsigned short wds[64 * DST];
  const int t = threadIdx.x;
  const int w = t >> 6, lane = t & 63;
  const int L15 = lane & 15, q = lane >> 4;
  const int r0 = blockIdx.x * 64;

#pragma unroll
  for (int rep = 0; rep < 8; ++rep) {
    int idx = rep * 256 + t, row = idx >> 5, c8 = (idx & 31) * 8;
    *(uint4*)&dxs[row * DST + c8] = *(const uint4*)&DX[(size_t)(r0 + row) * 256 + c8];
    *(uint4*)&wds[row * DST + c8] = *(const uint4*)&Wdb[(size_t)row * 256 + c8];
  }
  __syncthreads();

  f32x4 C[4];
#pragma unroll
  for (int nt = 0; nt < 4; ++nt) C[nt] = (f32x4){0.f, 0.f, 0.f, 0.f};
#pragma unroll
  for (int kt = 0; kt < 8; ++kt) {
    bf16x8 aD = *(bf16x8*)&dxs[(w * 16 + L15) * DST + kt * 32 + q * 8];
#pragma unroll
    for (int nt = 0; nt < 4; ++nt) {
      bf16x8 bW = *(bf16x8*)&wds[(nt * 16 + L15) * DST + kt * 32 + q * 8];
      C[nt] = __builtin_amdgcn_mfma_f32_16x16x32_bf16(aD, bW, C[nt], 0, 0, 0);
    }
  }
#pragma unroll
  for (int nt = 0; nt < 4; ++nt) {
    float bb = bdec[nt * 16 + L15];
#pragma unroll
    for (int r = 0; r < 4; ++r)
      out[(size_t)(r0 + w * 16 + q * 4 + r) * DD + nt * 16 + L15] = C[nt][r] + bb;
  }
}

extern "C" void kernel_launch(void* const* d_in, const int* in_sizes, int n_in,
                              void* d_out, int out_size, void* d_ws, size_t ws_size,
                              hipStream_t stream) {
  const float* x    = (const float*)d_in[0];
  const float* Wk   = (const float*)d_in[2];
  const float* bk   = (const float*)d_in[3];
  const float* Wq   = (const float*)d_in[4];
  const float* bq   = (const float*)d_in[5];
  const float* Wv   = (const float*)d_in[6];
  const float* bv   = (const float*)d_in[7];
  const float* Wdec = (const float*)d_in[8];
  const float* bdec = (const float*)d_in[9];
  float* out = (float*)d_out;

  // ws (shorts): Khi|Klo|Qhi|Qlo|Vt|DX (seg each) then Whi|Wlo (3*16384) | Wdb (16384)
  const size_t seg = (size_t)NB * HH * MM * DD;
  unsigned short* Khi = (unsigned short*)d_ws;
  unsigned short* Klo = Khi + seg;
  unsigned short* Qhi = Klo + seg;
  unsigned short* Qlo = Qhi + seg;
  unsigned short* Vt  = Qlo + seg;
  unsigned short* DXp = Vt + seg;
  unsigned short* Whi = DXp + seg;
  unsigned short* Wlo = Whi + 3 * 16384;
  unsigned short* Wdb = Wlo + 3 * 16384;

  prep_kernel<<<64, 256, 0, stream>>>(Wk, Wq, Wv, Wdec, Whi, Wlo, Wdb);
  proj_kernel<<<dim3(256, 12), 256, 0, stream>>>(x, Whi, Wlo, bk, bq, bv,
                                                 Khi, Klo, Qhi, Qlo, Vt);
  attn_kernel<<<dim3(16, HH, NB), 256, 0, stream>>>(Khi, Klo, Qhi, Qlo, Vt, x, DXp);
  dec_kernel<<<NB * MM / 64, 256, 0, stream>>>(DXp, Wdb, bdec, out);
}

// Round 4
// 162.059 us; speedup vs baseline: 7.9067x; 1.2398x over previous
//
#include <hip/hip_runtime.h>
#include <hip/hip_bf16.h>

// Node_GAT N=16, M=1024, D=64, H=4.
// R4: 32x32x16 MFMA everywhere (2x LDS-byte efficiency vs 16x16 — R3 was
// LDS-instruction-throughput-bound). S/proj/dec in single f16 (err ~0.011 in S,
// well under threshold); P stays bf16 (exp range). Max-free softmax as before.

#define NB 16
#define MM 1024
#define DD 64
#define HH 4
#define NEG 0.2f
#define AST 72   // LDS row stride (shorts): 16B-aligned rows; 2*AST = 16 dwords mod 32
#define DST 264  // dec LDS stride (256-wide rows)

typedef __attribute__((ext_vector_type(8))) short bf16x8;
typedef __attribute__((ext_vector_type(8))) _Float16 f16x8;
typedef __attribute__((ext_vector_type(16))) float f32x16;

__device__ inline unsigned short f2bf(float f) {
  unsigned int u = __builtin_bit_cast(unsigned int, f);
  unsigned int r = (u + 0x7FFFu + ((u >> 16) & 1u)) >> 16;
  return (unsigned short)r;
}
__device__ inline unsigned short f2h(float f) {
  _Float16 h = (_Float16)f;
  return __builtin_bit_cast(unsigned short, h);
}

// ---------------- Kernel 0: weight prep -> f16 ----------------
// Wk|Wq|Wv|Wdec (16384 fp32 each) -> Wf[4*16384] f16, contiguous.
__global__ __launch_bounds__(256) void prep_kernel(
    const float* __restrict__ Wk, const float* __restrict__ Wq,
    const float* __restrict__ Wv, const float* __restrict__ Wdec,
    unsigned short* __restrict__ Wf) {
  const int idx = (blockIdx.x * 256 + threadIdx.x) * 4;
  const int seg = idx >> 14, local = idx & 16383;
  const float* src = seg == 0 ? Wk : seg == 1 ? Wq : seg == 2 ? Wv : Wdec;
  float4 v = *(const float4*)&src[local];
  unsigned short p[4] = {f2h(v.x), f2h(v.y), f2h(v.z), f2h(v.w)};
  *(uint2*)&Wf[idx] = *(uint2*)p;
}

// ---------------- Kernel 1: projections, f16 32x32x16 MFMA ----------------
// grid (256, 12): 64 m-rows x combo(mat*4+h). K,Q -> f16 (n,h,m,e); V -> bf16 Vt (n,h,e,m).
__global__ __launch_bounds__(256) void proj_kernel(
    const float* __restrict__ x, const unsigned short* __restrict__ Wf,
    const float* __restrict__ bk, const float* __restrict__ bq, const float* __restrict__ bv,
    unsigned short* __restrict__ Kf, unsigned short* __restrict__ Qf,
    unsigned short* __restrict__ Vtg) {
  __shared__ unsigned short xs[64 * AST];
  __shared__ unsigned short ob[64 * AST];
  const int t = threadIdx.x;
  const int r0 = blockIdx.x * 64;
  const int combo = blockIdx.y, mat = combo >> 2, h = combo & 3;
  const int n = r0 >> 10, ml = r0 & 1023;
  const float* bias = mat == 0 ? bk : (mat == 1 ? bq : bv);

  // stage x tile as f16
#pragma unroll
  for (int rep = 0; rep < 2; ++rep) {
    int idx = rep * 256 + t, row = idx >> 3, c8 = (idx & 7) * 8;
    float4 a = *(const float4*)&x[(size_t)(r0 + row) * DD + c8];
    float4 b = *(const float4*)&x[(size_t)(r0 + row) * DD + c8 + 4];
    unsigned short p[8] = {f2h(a.x), f2h(a.y), f2h(a.z), f2h(a.w),
                           f2h(b.x), f2h(b.y), f2h(b.z), f2h(b.w)};
    *(uint4*)&xs[row * AST + c8] = *(uint4*)p;
  }
  __syncthreads();

  const int w = t >> 6, lane = t & 63, m31 = lane & 31, hf = lane >> 5;
  const int mi = w >> 1, ne = w & 1;  // wave tile: rows mi*32.., cols ne*32..
  const int ecol = h * 64 + ne * 32 + m31;
  const float bb = bias[ecol];

  f32x16 C;
#pragma unroll
  for (int r = 0; r < 16; ++r) C[r] = 0.f;
#pragma unroll
  for (int ks = 0; ks < 4; ++ks) {
    f16x8 xa = *(f16x8*)&xs[(mi * 32 + m31) * AST + ks * 16 + hf * 8];
    f16x8 wb = *(const f16x8*)&Wf[(size_t)mat * 16384 + (size_t)ecol * DD + ks * 16 + hf * 8];
    C = __builtin_amdgcn_mfma_f32_32x32x16_f16(xa, wb, C, 0, 0, 0);
  }

  if (mat < 2) {
#pragma unroll
    for (int r = 0; r < 16; ++r) {
      int rr = (r & 3) + 8 * (r >> 2) + 4 * hf;
      ob[(mi * 32 + rr) * AST + ne * 32 + m31] = f2h(C[r] + bb);
    }
  } else {
    // V transposed: ob[e][m_local], bf16
#pragma unroll
    for (int r = 0; r < 16; ++r) {
      int rr = (r & 3) + 8 * (r >> 2) + 4 * hf;
      ob[(ne * 32 + m31) * AST + mi * 32 + rr] = f2bf(C[r] + bb);
    }
  }
  __syncthreads();

  if (mat < 2) {
    unsigned short* dst = mat == 0 ? Kf : Qf;
    const size_t obase = (((size_t)n * HH + h) * MM + ml) * DD;
#pragma unroll
    for (int rep = 0; rep < 2; ++rep) {
      int idx = rep * 256 + t, row = idx >> 3, c8 = (idx & 7) * 8;
      *(uint4*)&dst[obase + (size_t)row * DD + c8] = *(uint4*)&ob[row * AST + c8];
    }
  } else {
    const size_t obase = (((size_t)n * HH + h) * DD) * MM + ml;
#pragma unroll
    for (int rep = 0; rep < 2; ++rep) {
      int idx = rep * 256 + t, row = idx >> 3, c8 = (idx & 7) * 8;  // row = e
      *(uint4*)&Vtg[obase + (size_t)row * MM + c8] = *(uint4*)&ob[row * AST + c8];
    }
  }
}

// ---------------- Kernel 2: flash attention, 32x32x16 ----------------
// grid (16, H, N), 256 thr = 4 waves. Block: 64 i x 1024 j.
// Wave w: tile (ti = w>>1, tw = w&1). S: (i-tile ti, j-half tw); PV: (i-tile ti, e-half tw).
__global__ __launch_bounds__(256, 4) void attn_kernel(
    const unsigned short* __restrict__ Kf, const unsigned short* __restrict__ Qf,
    const unsigned short* __restrict__ Vtg, const float* __restrict__ x,
    unsigned short* __restrict__ DX) {
  __shared__ unsigned short qh[64 * AST];  // Q f16 [j][e]
  __shared__ unsigned short vt[64 * AST];  // V^T bf16 [e][j]
  __shared__ unsigned short ps[64 * AST];  // P bf16 [i][j]; reused for dx f16
  __shared__ float ls[64];

  const int t = threadIdx.x;
  const int w = t >> 6, lane = t & 63;
  const int m31 = lane & 31, hf = lane >> 5;
  const int ti = w >> 1, tw = w & 1;
  const int i0 = blockIdx.x * 64, h = blockIdx.y, n = blockIdx.z;
  const size_t base = (((size_t)n * HH + h) * MM) * DD;
  const size_t baseT = (((size_t)n * HH + h) * DD) * MM;

  // K A-frags from global f16 (rows exclusive to this wave), held in registers
  f16x8 kfrag[4];
#pragma unroll
  for (int ks = 0; ks < 4; ++ks)
    kfrag[ks] = *(const f16x8*)&Kf[base + (size_t)(i0 + ti * 32 + m31) * DD + ks * 16 + hf * 8];

  f32x16 agg, accl;
#pragma unroll
  for (int r = 0; r < 16; ++r) { agg[r] = 0.f; accl[r] = 0.f; }
  bf16x8 ones;
#pragma unroll
  for (int r = 0; r < 8; ++r) ones[r] = (short)0x3F80;

  for (int jt = 0; jt < 16; ++jt) {
    const int j0 = jt * 64;
    __syncthreads();  // prev PV done: safe to restage & rewrite ps
#pragma unroll
    for (int rep = 0; rep < 2; ++rep) {
      int idx = rep * 256 + t, row = idx >> 3, c8 = (idx & 7) * 8;
      *(uint4*)&qh[row * AST + c8] = *(const uint4*)&Qf[base + (size_t)(j0 + row) * DD + c8];
      *(uint4*)&vt[row * AST + c8] = *(const uint4*)&Vtg[baseT + (size_t)row * MM + j0 + c8];
    }
    __syncthreads();

    // S tile (32i x 32j): 4 MFMA; leaky+exp -> P bf16 in LDS
    f32x16 C;
#pragma unroll
    for (int r = 0; r < 16; ++r) C[r] = 0.f;
#pragma unroll
    for (int ks = 0; ks < 4; ++ks) {
      f16x8 qf = *(f16x8*)&qh[(tw * 32 + m31) * AST + ks * 16 + hf * 8];
      C = __builtin_amdgcn_mfma_f32_32x32x16_f16(kfrag[ks], qf, C, 0, 0, 0);
    }
#pragma unroll
    for (int r = 0; r < 16; ++r) {
      float s = C[r];
      s = s > 0.f ? s : NEG * s;
      int rr = (r & 3) + 8 * (r >> 2) + 4 * hf;
      ps[(ti * 32 + rr) * AST + tw * 32 + m31] = f2bf(__expf(s));
    }
    __syncthreads();  // PV A-frags span both j-halves (cross-wave P)

    // PV tile (32i x 32e) + l via ones-MFMA (waves tw==0 only)
#pragma unroll
    for (int ks = 0; ks < 4; ++ks) {
      bf16x8 aP = *(bf16x8*)&ps[(ti * 32 + m31) * AST + ks * 16 + hf * 8];
      bf16x8 bV = *(bf16x8*)&vt[(tw * 32 + m31) * AST + ks * 16 + hf * 8];
      agg = __builtin_amdgcn_mfma_f32_32x32x16_bf16(aP, bV, agg, 0, 0, 0);
      if (tw == 0)
        accl = __builtin_amdgcn_mfma_f32_32x32x16_bf16(aP, ones, accl, 0, 0, 0);
    }
  }

  // share l rows via LDS (accl cols identical; lane m31==0 writes)
  if (tw == 0 && m31 == 0) {
#pragma unroll
    for (int r = 0; r < 16; ++r) {
      int rr = (r & 3) + 8 * (r >> 2) + 4 * hf;
      ls[ti * 32 + rr] = accl[r];
    }
  }
  __syncthreads();

  // epilogue: dx = leaky(agg/l) - x -> f16 in ps -> coalesced store (concat layout)
#pragma unroll
  for (int r = 0; r < 16; ++r) {
    int rr = (r & 3) + 8 * (r >> 2) + 4 * hf;
    float l = ls[ti * 32 + rr];
    float v = agg[r] / l;
    v = v > 0.f ? v : NEG * v;
    v -= x[((size_t)n * MM + i0 + ti * 32 + rr) * DD + tw * 32 + m31];
    ps[(ti * 32 + rr) * AST + tw * 32 + m31] = f2h(v);
  }
  __syncthreads();
#pragma unroll
  for (int rep = 0; rep < 2; ++rep) {
    int idx = rep * 256 + t, row = idx >> 3, c8 = (idx & 7) * 8;
    *(uint4*)&DX[((size_t)n * MM + i0 + row) * (HH * DD) + h * DD + c8] =
        *(uint4*)&ps[row * AST + c8];
  }
}

// ---------------- Kernel 3: decoder, f16 32x32x16 MFMA ----------------
// out(16384x64) = dx(16384x256 f16) . Wdec^T + b. 64 rows/block.
__global__ __launch_bounds__(256) void dec_kernel(
    const unsigned short* __restrict__ DX, const unsigned short* __restrict__ Wdf,
    const float* __restrict__ bdec, float* __restrict__ out) {
  __shared__ unsigned short dxs[64 * DST];
  const int t = threadIdx.x;
  const int w = t >> 6, lane = t & 63, m31 = lane & 31, hf = lane >> 5;
  const int mi = w >> 1, nd = w & 1;
  const int r0 = blockIdx.x * 64;
#pragma unroll
  for (int rep = 0; rep < 8; ++rep) {
    int idx = rep * 256 + t, row = idx >> 5, c8 = (idx & 31) * 8;
    *(uint4*)&dxs[row * DST + c8] = *(const uint4*)&DX[(size_t)(r0 + row) * 256 + c8];
  }
  __syncthreads();
  const float bb = bdec[nd * 32 + m31];
  f32x16 C;
#pragma unroll
  for (int r = 0; r < 16; ++r) C[r] = 0.f;
#pragma unroll
  for (int ks = 0; ks < 16; ++ks) {
    f16x8 aD = *(f16x8*)&dxs[(mi * 32 + m31) * DST + ks * 16 + hf * 8];
    f16x8 bW = *(const f16x8*)&Wdf[(size_t)(nd * 32 + m31) * 256 + ks * 16 + hf * 8];
    C = __builtin_amdgcn_mfma_f32_32x32x16_f16(aD, bW, C, 0, 0, 0);
  }
#pragma unroll
  for (int r = 0; r < 16; ++r) {
    int rr = (r & 3) + 8 * (r >> 2) + 4 * hf;
    out[(size_t)(r0 + mi * 32 + rr) * DD + nd * 32 + m31] = C[r] + bb;
  }
}

extern "C" void kernel_launch(void* const* d_in, const int* in_sizes, int n_in,
                              void* d_out, int out_size, void* d_ws, size_t ws_size,
                              hipStream_t stream) {
  const float* x    = (const float*)d_in[0];
  const float* Wk   = (const float*)d_in[2];
  const float* bk   = (const float*)d_in[3];
  const float* Wq   = (const float*)d_in[4];
  const float* bq   = (const float*)d_in[5];
  const float* Wv   = (const float*)d_in[6];
  const float* bv   = (const float*)d_in[7];
  const float* Wdec = (const float*)d_in[8];
  const float* bdec = (const float*)d_in[9];
  float* out = (float*)d_out;

  // ws (shorts): Kf | Qf | Vt | DX (seg each), then Wf (4*16384: K,Q,V,dec f16)
  const size_t seg = (size_t)NB * HH * MM * DD;
  unsigned short* Kf  = (unsigned short*)d_ws;
  unsigned short* Qf  = Kf + seg;
  unsigned short* Vt  = Qf + seg;
  unsigned short* DXp = Vt + seg;
  unsigned short* Wf  = DXp + seg;
  unsigned short* Wdf = Wf + 3 * 16384;

  prep_kernel<<<64, 256, 0, stream>>>(Wk, Wq, Wv, Wdec, Wf);
  proj_kernel<<<dim3(256, 12), 256, 0, stream>>>(x, Wf, bk, bq, bv, Kf, Qf, Vt);
  attn_kernel<<<dim3(16, HH, NB), 256, 0, stream>>>(Kf, Qf, Vt, x, DXp);
  dec_kernel<<<NB * MM / 64, 256, 0, stream>>>(DXp, Wdf, bdec, out);
}